// Round 8
// baseline (137.607 us; speedup 1.0000x reference)
//
#include <hip/hip_runtime.h>

// LogSignature depth-4, C=16, B=64, L=256, fp32.
// out per batch: [lvl1(16) | lvl2(256) | lvl3(4096) | lvl4(65536)] = 69904
//
// v9: v4's proven all-LDS scan structure (best measured: 48.5us; VMEM-row
// variants refuted in R5/R7) at DOUBLE the wave count.
// k_scan: block (j,a), 512 threads = {qc(2b)|b(4b)|c0(3b)}; 4-way in-block
//   time split (Chen), 64 steps/chunk; step 255 zero-padded (uniform loop).
//   Per-thread c-pair (c0,c0+8). Rows via uniform ds_read_b128 broadcast from
//   Lp; streams via conflict-lite b128 from Lc (stride 260). Inner 32 FMAs as
//   16 v_pk_fma_f32. 1024 blocks x 512thr: LDS 33KB -> 4 blocks/CU; if the
//   compiler holds VGPR<=64 (it did for this body in v4/v7) -> 32 waves/CU,
//   double v4's 16. launch_bounds(512,4) only — NO forced register budget
//   (v5's (512,8) coercion caused a 640MB scratch spill disaster).
//   Epilogue: 4 chunks' pure-L4 sums merged in LDS, one 16KB write; per-chunk
//   sig123 -> ws.
// k_log: v5's verified 3-stage Chen merge (M <- M (x) X_s) + log correction.
//
// ws (floats): sig [4][64][4368] ~ 4.5 MB.

#define NC 16
#define NL 256
#define NB 64
#define OUTB 69904
#define SIG123 4368
#define OFF_L2 16
#define OFF_L3 272
#define OFF_L4 4368
#define LCS 260  // padded component-major stride: (260 mod 32)=4 -> conflict-lite

typedef float v2f __attribute__((ext_vector_type(2)));

__global__ __launch_bounds__(512, 4) void k_scan(const float* __restrict__ path,
                                                 float* __restrict__ out,
                                                 float* __restrict__ sig) {
    const int bid = blockIdx.x;
    const int j = bid >> 4;
    const int a = bid & 15;
    const int tid = threadIdx.x;
    const int qc = tid >> 7;         // time chunk 0..3 -> steps [qc*64, qc*64+64)
    const int b = (tid >> 3) & 15;
    const int c0 = tid & 7;          // owns c0 and c0+8

    __shared__ float Lp[NL * NC];    // path -> time-major diffs (in place); later merge buf
    __shared__ float Lc[NC * LCS];   // component-major diffs [i][t]

    // ---- stage path[j] (16 KB, coalesced; 2 float4 per thread) ----
    const float* pj = path + (size_t)j * NL * NC;
#pragma unroll
    for (int k = 0; k < 2; ++k) {
        const int f = tid + k * 512;
        *(float4*)&Lp[f * 4] = *(const float4*)&pj[f * 4];
    }
    __syncthreads();

    // ---- diffs; step 255 zero-padded (exact identity step) ----
    float4 dif[2];
#pragma unroll
    for (int k = 0; k < 2; ++k) {
        const int f = tid + k * 512;  // float4 index 0..1023
        if (f < 1020) {
            const float4 x0 = *(const float4*)&Lp[f * 4];
            const float4 x1 = *(const float4*)&Lp[f * 4 + 16];
            dif[k] = make_float4(x1.x - x0.x, x1.y - x0.y, x1.z - x0.z, x1.w - x0.w);
        } else {
            dif[k] = make_float4(0.f, 0.f, 0.f, 0.f);
        }
    }
    __syncthreads();
#pragma unroll
    for (int k = 0; k < 2; ++k) {
        const int f = tid + k * 512;
        *(float4*)&Lp[f * 4] = dif[k];
        const int t = f >> 2;            // time index 0..255
        const int i0 = 4 * (f & 3);      // component base
        Lc[(i0 + 0) * LCS + t] = dif[k].x;
        Lc[(i0 + 1) * LCS + t] = dif[k].y;
        Lc[(i0 + 2) * LCS + t] = dif[k].z;
        Lc[(i0 + 3) * LCS + t] = dif[k].w;
    }
    __syncthreads();

    // ---- chunk-local scan: 64 steps ----
    v2f s4a[8], s4b[8];
#pragma unroll
    for (int d = 0; d < 8; ++d) { s4a[d] = (v2f){0.f, 0.f}; s4b[d] = (v2f){0.f, 0.f}; }
    float s3_0 = 0.f, s3_1 = 0.f, s2ab = 0.f, s1a = 0.f;

    int t = qc * 64;
    for (int it = 0; it < 16; ++it, t += 4) {
        const float4 va = *(const float4*)(Lc + a * LCS + t);    // broadcast
        const float4 vb = *(const float4*)(Lc + b * LCS + t);    // ~2-way
        const float4 vc0 = *(const float4*)(Lc + c0 * LCS + t);
        const float4 vc1 = *(const float4*)(Lc + (c0 + 8) * LCS + t);
#pragma unroll
        for (int u = 0; u < 4; ++u) {
            const float* r = Lp + (t + u) * NC;   // uniform row, b128 broadcast
            const float4 q0 = *(const float4*)(r);
            const float4 q1 = *(const float4*)(r + 4);
            const float4 q2 = *(const float4*)(r + 8);
            const float4 q3 = *(const float4*)(r + 12);
            const float dxa = (u == 0) ? va.x : (u == 1) ? va.y : (u == 2) ? va.z : va.w;
            const float dxb = (u == 0) ? vb.x : (u == 1) ? vb.y : (u == 2) ? vb.z : vb.w;
            const float dxc0 = (u == 0) ? vc0.x : (u == 1) ? vc0.y : (u == 2) ? vc0.z : vc0.w;
            const float dxc1 = (u == 0) ? vc1.x : (u == 1) ? vc1.y : (u == 2) ? vc1.z : vc1.w;

            const float P = dxb * s1a;
            const float Q = dxb * dxa;
            const float pre4 = fmaf(1.f / 6.f, P, fmaf(1.f / 24.f, Q, 0.5f * s2ab));
            const float U = fmaf(0.5f, P, fmaf(1.f / 6.f, Q, s2ab));
            const float T0 = fmaf(dxc0, pre4, s3_0);
            const float T1 = fmaf(dxc1, pre4, s3_1);

            const v2f dv2[8] = {{q0.x, q0.y}, {q0.z, q0.w}, {q1.x, q1.y}, {q1.z, q1.w},
                                {q2.x, q2.y}, {q2.z, q2.w}, {q3.x, q3.y}, {q3.z, q3.w}};
            const v2f T0v = {T0, T0};
            const v2f T1v = {T1, T1};
#pragma unroll
            for (int d = 0; d < 8; ++d) {
                s4a[d] = __builtin_elementwise_fma(dv2[d], T0v, s4a[d]);  // v_pk_fma_f32
                s4b[d] = __builtin_elementwise_fma(dv2[d], T1v, s4b[d]);
            }
            s3_0 = fmaf(dxc0, U, s3_0);
            s3_1 = fmaf(dxc1, U, s3_1);
            s2ab = fmaf(dxb, fmaf(0.5f, dxa, s1a), s2ab);
            s1a += dxa;
        }
    }

    // ---- epilogue: sum 4 chunks' pure L4 in LDS (Lp reused), one write ----
    __syncthreads();
    float* ls = Lp;
    const int base = b * 256 + c0 * 16;
#pragma unroll
    for (int ph = 0; ph < 4; ++ph) {
        if (qc == ph) {
            if (ph == 0) {
#pragma unroll
                for (int d = 0; d < 4; ++d) {
                    *(float4*)&ls[base + d * 4] = make_float4(
                        s4a[2 * d].x, s4a[2 * d].y, s4a[2 * d + 1].x, s4a[2 * d + 1].y);
                    *(float4*)&ls[base + 128 + d * 4] = make_float4(
                        s4b[2 * d].x, s4b[2 * d].y, s4b[2 * d + 1].x, s4b[2 * d + 1].y);
                }
            } else {
#pragma unroll
                for (int d = 0; d < 4; ++d) {
                    float4 v0 = *(const float4*)&ls[base + d * 4];
                    v0.x += s4a[2 * d].x; v0.y += s4a[2 * d].y;
                    v0.z += s4a[2 * d + 1].x; v0.w += s4a[2 * d + 1].y;
                    *(float4*)&ls[base + d * 4] = v0;
                    float4 v1 = *(const float4*)&ls[base + 128 + d * 4];
                    v1.x += s4b[2 * d].x; v1.y += s4b[2 * d].y;
                    v1.z += s4b[2 * d + 1].x; v1.w += s4b[2 * d + 1].y;
                    *(float4*)&ls[base + 128 + d * 4] = v1;
                }
            }
        }
        __syncthreads();
    }
    {
        float* o4 = out + (size_t)j * OUTB + OFF_L4 + a * 4096;
#pragma unroll
        for (int k = 0; k < 2; ++k) {
            const int f = tid + k * 512;  // float4 index 0..1023
            *(float4*)(o4 + f * 4) = *(const float4*)&ls[f * 4];
        }
    }

    // ---- levels 1-3 of this thread's chunk ----
    float* sg = sig + ((size_t)qc * NB + j) * SIG123;
    sg[OFF_L3 + (a * 16 + b) * 16 + c0] = s3_0;
    sg[OFF_L3 + (a * 16 + b) * 16 + c0 + 8] = s3_1;
    if (c0 == 0) sg[OFF_L2 + a * 16 + b] = s2ab;
    if ((tid & 127) == 0) sg[a] = s1a;
}

// 3-stage Chen merge of the 4 chunk signatures + log correction (v5, verified).
__global__ __launch_bounds__(256, 4) void k_log(const float* __restrict__ sig,
                                                float* __restrict__ out) {
    const int bid = blockIdx.x;
    const int j = bid >> 4;
    const int a = bid & 15;
    const int tid = threadIdx.x;
    const int p16 = tid >> 4;
    const int r16 = tid & 15;

    __shared__ float M1[16];
    __shared__ float M2[256];
    __shared__ float M3[4096];

    const float* X0 = sig + (size_t)j * SIG123;
    if (tid < 16) M1[tid] = X0[tid];
    M2[tid] = X0[OFF_L2 + tid];
#pragma unroll
    for (int k = 0; k < 16; ++k) M3[k * 256 + tid] = X0[OFF_L3 + k * 256 + tid];

    float4 acc[4];
#pragma unroll
    for (int k = 0; k < 4; ++k) acc[k] = make_float4(0.f, 0.f, 0.f, 0.f);
    __syncthreads();

    for (int s = 1; s < 4; ++s) {
        const float* Xs = sig + ((size_t)s * NB + j) * SIG123;
        const float m1a = M1[a];
        float4 m3n[4];
#pragma unroll
        for (int k = 0; k < 4; ++k) {
            const int f = tid + k * 256;   // float4 index 0..1023
            const int m0 = f * 4;          // element offset: bb*256 + cc*16 + d0
            const int bb = m0 >> 8;
            const int cc = (m0 >> 4) & 15;
            const float4 x3 = *(const float4*)(Xs + OFF_L3 + m0);
            const float4 x2 = *(const float4*)(Xs + OFF_L2 + (m0 & 255));
            const float4 x1 = *(const float4*)(Xs + (m0 & 15));
            const float4 m3f = *(const float4*)(&M3[m0]);
            const float m2ab = M2[a * 16 + bb];
            const float m3abc = M3[a * 256 + (m0 >> 4)];
            const float m2pq = M2[bb * 16 + cc];
            const float m1p = M1[bb];
            // level-4 cross terms (old M x new chunk)
            acc[k].x += fmaf(m1a, x3.x, fmaf(m2ab, x2.x, m3abc * x1.x));
            acc[k].y += fmaf(m1a, x3.y, fmaf(m2ab, x2.y, m3abc * x1.y));
            acc[k].z += fmaf(m1a, x3.z, fmaf(m2ab, x2.z, m3abc * x1.z));
            acc[k].w += fmaf(m1a, x3.w, fmaf(m2ab, x2.w, m3abc * x1.w));
            // level-3 merge: M3' = M3 + X3 + M1 x X2 + M2 x X1
            m3n[k].x = m3f.x + x3.x + fmaf(m1p, x2.x, m2pq * x1.x);
            m3n[k].y = m3f.y + x3.y + fmaf(m1p, x2.y, m2pq * x1.y);
            m3n[k].z = m3f.z + x3.z + fmaf(m1p, x2.z, m2pq * x1.z);
            m3n[k].w = m3f.w + x3.w + fmaf(m1p, x2.w, m2pq * x1.w);
        }
        const float m2new = M2[tid] + Xs[OFF_L2 + tid] + M1[p16] * Xs[r16];
        float m1new = 0.f;
        if (tid < 16) m1new = M1[tid] + Xs[tid];
        __syncthreads();
#pragma unroll
        for (int k = 0; k < 4; ++k) *(float4*)(&M3[(tid + k * 256) * 4]) = m3n[k];
        M2[tid] = m2new;
        if (tid < 16) M1[tid] = m1new;
        __syncthreads();
    }

    // log correction on merged S (= M), RMW on out L4 (holds sum of pure X4).
    const float s1a = M1[a];
    float* outj = out + (size_t)j * OUTB;
    float* o4 = outj + OFF_L4 + a * 4096;
    const float Ac = -0.5f * s1a;

#pragma unroll
    for (int k = 0; k < 4; ++k) {
        const int f = tid + k * 256;
        const int m0 = f * 4;
        const int bb = m0 >> 8;
        const int cc = (m0 >> 4) & 15;
        const float s1b = M1[bb], s1c = M1[cc];
        const float s2ab = M2[a * 16 + bb];
        const float s2bc = M2[bb * 16 + cc];
        const float s3abc = M3[a * 256 + (m0 >> 4)];

        const float4 p4 = *(const float4*)(o4 + m0);
        const float4 v3 = *(const float4*)(&M3[m0]);
        const float4 v2 = *(const float4*)(&M2[m0 & 255]);
        const float4 v1 = *(const float4*)(&M1[m0 & 15]);

        const float Bv = fmaf((1.f / 3.f) * s1a, s1b, -0.5f * s2ab);
        const float Cv = -0.5f * s3abc + (1.f / 3.f) * fmaf(s1a, s2bc, s2ab * s1c)
                         - 0.25f * s1a * s1b * s1c;
        float4 rr;
        rr.x = p4.x + acc[k].x;
        rr.y = p4.y + acc[k].y;
        rr.z = p4.z + acc[k].z;
        rr.w = p4.w + acc[k].w;
        rr.x = fmaf(Ac, v3.x, rr.x) + fmaf(Bv, v2.x, Cv * v1.x);
        rr.y = fmaf(Ac, v3.y, rr.y) + fmaf(Bv, v2.y, Cv * v1.y);
        rr.z = fmaf(Ac, v3.z, rr.z) + fmaf(Bv, v2.z, Cv * v1.z);
        rr.w = fmaf(Ac, v3.w, rr.w) + fmaf(Bv, v2.w, Cv * v1.w);
        *(float4*)(o4 + m0) = rr;
    }

    // level 3 (coalesced): s2bc = M2[tid] since tid = b*16+c here.
    {
        const float s1b = M1[p16], s1c = M1[r16];
        const float s2ab = M2[a * 16 + p16];
        const float s2bc = M2[tid];
        const float s3abc = M3[a * 256 + tid];
        const float r3 = s3abc - 0.5f * fmaf(s1a, s2bc, s2ab * s1c)
                         + (1.f / 3.f) * s1a * s1b * s1c;
        outj[OFF_L3 + a * 256 + tid] = r3;
    }
    // level 2
    if (tid < 16) outj[OFF_L2 + a * 16 + tid] = fmaf(-0.5f * s1a, M1[tid], M2[a * 16 + tid]);
    // level 1
    if (tid == 0) outj[a] = s1a;
}

extern "C" void kernel_launch(void* const* d_in, const int* in_sizes, int n_in,
                              void* d_out, int out_size, void* d_ws, size_t ws_size,
                              hipStream_t stream) {
    const float* path = (const float*)d_in[0];
    float* out = (float*)d_out;
    float* sig = (float*)d_ws;

    k_scan<<<NB * 16, 512, 0, stream>>>(path, out, sig);
    k_log<<<NB * 16, 256, 0, stream>>>(sig, out);
}

// Round 9
// 105.891 us; speedup vs baseline: 1.2995x; 1.2995x over previous
//
#include <hip/hip_runtime.h>

// LogSignature depth-4, C=16, B=64, L=256, fp32.
// out per batch: [lvl1(16) | lvl2(256) | lvl3(4096) | lvl4(65536)] = 69904
//
// v10: attack the DS-pipe roofline (R8 proved k_scan is bound by the per-CU
// LDS pipe: 20 b128/4-steps/wave * 12cyc * 4 blk/CU = 51us = the plateau;
// occupancy-doubling changed nothing). Row-read count scales as 1/A where
// A = accumulator outputs per thread:
// k_scan: block (j,a), 128 threads = {h(1b)|b(4b)|c0(2b)}, 2 waves. Thread
//   owns a c-QUAD {c0,c0+4,c0+8,c0+12} -> A=64 (s4 = 4x16 = 32 v2f), halving
//   uniform row b128s vs v4's c-pair: each chunk's rows read EXACTLY once per
//   block. DS/CU ~ 67k cyc ~ 28us. Streams from Lc (stride 260); rows from
//   Lp (uniform b128 broadcast). Inner 64 FMAs as 32 v_pk_fma_f32. Step 255
//   zero-padded -> uniform 32x4 loop. launch_bounds(128,2): 256-VGPR ceiling,
//   no forced-budget spill (v5 lesson). Epilogue: A4+B4 merged in a slot-65
//   padded LDS layout (conflict-free scatter), one coalesced 16KB write.
// k_log: v4's single-stage 2-chunk Chen merge + log correction (PROVEN ~8us;
//   the 3-stage variant was a hidden ~35us regression in R4/R8).
//
// ws (floats): sigA [64][4368] | sigB [64][4368]  (~2.2 MB)

#define NC 16
#define NL 256
#define NB 64
#define OUTB 69904
#define SIG123 4368
#define OFF_L2 16
#define OFF_L3 272
#define OFF_L4 4368
#define LCS 260  // padded component-major stride

#define SIGA_OFF 0
#define SIGB_OFF (NB * SIG123)

typedef float v2f __attribute__((ext_vector_type(2)));

__global__ __launch_bounds__(128, 2) void k_scan(const float* __restrict__ path,
                                                 float* __restrict__ out,
                                                 float* __restrict__ sigA,
                                                 float* __restrict__ sigB) {
    const int bid = blockIdx.x;
    const int j = bid >> 4;
    const int a = bid & 15;
    const int tid = threadIdx.x;
    const int h = tid >> 6;          // time chunk: 0 -> [0,128), 1 -> [128,256)
    const int b = (tid >> 2) & 15;
    const int c0 = tid & 3;          // owns c = c0, c0+4, c0+8, c0+12

    __shared__ float Lp[NL * NC];    // time-major diffs (in place over path)
    __shared__ float Lc[NC * LCS];   // component-major diffs [i][t]; reused as slot-65 merge buf

    // ---- stage path[j] (16 KB, coalesced; 8 float4 per thread) ----
    const float* pj = path + (size_t)j * NL * NC;
#pragma unroll
    for (int k = 0; k < 8; ++k) {
        const int f = tid + k * 128;
        *(float4*)&Lp[f * 4] = *(const float4*)&pj[f * 4];
    }
    __syncthreads();

    // ---- diffs; step 255 zero-padded (exact identity step) ----
    float4 dif[8];
#pragma unroll
    for (int k = 0; k < 8; ++k) {
        const int f = tid + k * 128;  // float4 index 0..1023
        if (f < 1020) {
            const float4 x0 = *(const float4*)&Lp[f * 4];
            const float4 x1 = *(const float4*)&Lp[f * 4 + 16];
            dif[k] = make_float4(x1.x - x0.x, x1.y - x0.y, x1.z - x0.z, x1.w - x0.w);
        } else {
            dif[k] = make_float4(0.f, 0.f, 0.f, 0.f);
        }
    }
    __syncthreads();
#pragma unroll
    for (int k = 0; k < 8; ++k) {
        const int f = tid + k * 128;
        *(float4*)&Lp[f * 4] = dif[k];
        const int t = f >> 2;            // time index 0..255
        const int i0 = 4 * (f & 3);      // component base
        Lc[(i0 + 0) * LCS + t] = dif[k].x;
        Lc[(i0 + 1) * LCS + t] = dif[k].y;
        Lc[(i0 + 2) * LCS + t] = dif[k].z;
        Lc[(i0 + 3) * LCS + t] = dif[k].w;
    }
    __syncthreads();

    // ---- chunk-local scan: 128 steps, c-quad accumulators ----
    v2f s4q[4][8];
#pragma unroll
    for (int m = 0; m < 4; ++m)
#pragma unroll
        for (int d = 0; d < 8; ++d) s4q[m][d] = (v2f){0.f, 0.f};
    float s3q[4] = {0.f, 0.f, 0.f, 0.f};
    float s2ab = 0.f, s1a = 0.f;

    auto body = [&](const float4& q0, const float4& q1, const float4& q2,
                    const float4& q3, float dxa, float dxb, float dc0, float dc1,
                    float dc2, float dc3) {
        const float P = dxb * s1a;
        const float Q = dxb * dxa;
        const float pre4 = fmaf(1.f / 6.f, P, fmaf(1.f / 24.f, Q, 0.5f * s2ab));
        const float U = fmaf(0.5f, P, fmaf(1.f / 6.f, Q, s2ab));
        const float T0 = fmaf(dc0, pre4, s3q[0]);
        const float T1 = fmaf(dc1, pre4, s3q[1]);
        const float T2 = fmaf(dc2, pre4, s3q[2]);
        const float T3 = fmaf(dc3, pre4, s3q[3]);
        const v2f dv2[8] = {{q0.x, q0.y}, {q0.z, q0.w}, {q1.x, q1.y}, {q1.z, q1.w},
                            {q2.x, q2.y}, {q2.z, q2.w}, {q3.x, q3.y}, {q3.z, q3.w}};
        const v2f Tv0 = {T0, T0}, Tv1 = {T1, T1}, Tv2 = {T2, T2}, Tv3 = {T3, T3};
#pragma unroll
        for (int d = 0; d < 8; ++d) {
            s4q[0][d] = __builtin_elementwise_fma(dv2[d], Tv0, s4q[0][d]);  // v_pk_fma_f32
            s4q[1][d] = __builtin_elementwise_fma(dv2[d], Tv1, s4q[1][d]);
            s4q[2][d] = __builtin_elementwise_fma(dv2[d], Tv2, s4q[2][d]);
            s4q[3][d] = __builtin_elementwise_fma(dv2[d], Tv3, s4q[3][d]);
        }
        s3q[0] = fmaf(dc0, U, s3q[0]);
        s3q[1] = fmaf(dc1, U, s3q[1]);
        s3q[2] = fmaf(dc2, U, s3q[2]);
        s3q[3] = fmaf(dc3, U, s3q[3]);
        s2ab = fmaf(dxb, fmaf(0.5f, dxa, s1a), s2ab);
        s1a += dxa;
    };

    int t = h * 128;
    for (int it = 0; it < 32; ++it, t += 4) {
        const float4 va = *(const float4*)(Lc + a * LCS + t);         // broadcast
        const float4 vb = *(const float4*)(Lc + b * LCS + t);
        const float4 vc0 = *(const float4*)(Lc + c0 * LCS + t);
        const float4 vc1 = *(const float4*)(Lc + (c0 + 4) * LCS + t);
        const float4 vc2 = *(const float4*)(Lc + (c0 + 8) * LCS + t);
        const float4 vc3 = *(const float4*)(Lc + (c0 + 12) * LCS + t);
#pragma unroll
        for (int u = 0; u < 4; ++u) {
            const float* r = Lp + (t + u) * NC;   // uniform row, b128 broadcast
            const float4 q0 = *(const float4*)(r);
            const float4 q1 = *(const float4*)(r + 4);
            const float4 q2 = *(const float4*)(r + 8);
            const float4 q3 = *(const float4*)(r + 12);
            const float dxa = (u == 0) ? va.x : (u == 1) ? va.y : (u == 2) ? va.z : va.w;
            const float dxb = (u == 0) ? vb.x : (u == 1) ? vb.y : (u == 2) ? vb.z : vb.w;
            const float d0 = (u == 0) ? vc0.x : (u == 1) ? vc0.y : (u == 2) ? vc0.z : vc0.w;
            const float d1 = (u == 0) ? vc1.x : (u == 1) ? vc1.y : (u == 2) ? vc1.z : vc1.w;
            const float d2 = (u == 0) ? vc2.x : (u == 1) ? vc2.y : (u == 2) ? vc2.z : vc2.w;
            const float d3 = (u == 0) ? vc3.x : (u == 1) ? vc3.y : (u == 2) ? vc3.z : vc3.w;
            body(q0, q1, q2, q3, dxa, dxb, d0, d1, d2, d3);
        }
    }

    // ---- epilogue: merge A4+B4 in slot-65 LDS layout (conflict-free) ----
    // slot = b*4 + c0 (0..63); within slot: m*16 + d (m = c>>2). Lc reused.
    __syncthreads();
    float* sl = Lc + (size_t)(b * 4 + c0) * 65;
    if (h == 0) {
#pragma unroll
        for (int m = 0; m < 4; ++m)
#pragma unroll
            for (int q = 0; q < 4; ++q)
                *(float4*)&sl[m * 16 + q * 4] =
                    make_float4(s4q[m][2 * q].x, s4q[m][2 * q].y,
                                s4q[m][2 * q + 1].x, s4q[m][2 * q + 1].y);
    }
    __syncthreads();
    if (h == 1) {
#pragma unroll
        for (int m = 0; m < 4; ++m)
#pragma unroll
            for (int q = 0; q < 4; ++q) {
                float4 v = *(const float4*)&sl[m * 16 + q * 4];
                v.x += s4q[m][2 * q].x;
                v.y += s4q[m][2 * q].y;
                v.z += s4q[m][2 * q + 1].x;
                v.w += s4q[m][2 * q + 1].y;
                *(float4*)&sl[m * 16 + q * 4] = v;
            }
    }
    __syncthreads();
    {
        float* o4 = out + (size_t)j * OUTB + OFF_L4 + a * 4096;
#pragma unroll
        for (int k = 0; k < 8; ++k) {
            const int f = tid + k * 128;  // float4 index 0..1023
            const int m0 = f * 4;         // element offset: bb*256 + cc*16 + dd
            const int bb = m0 >> 8;
            const int cc = (m0 >> 4) & 15;
            const int dd = m0 & 15;
            const int src = (bb * 4 + (cc & 3)) * 65 + (cc >> 2) * 16 + dd;
            *(float4*)(o4 + m0) = *(const float4*)&Lc[src];
        }
    }

    // ---- levels 1-3 of this thread's chunk ----
    float* sg = (h ? sigB : sigA) + (size_t)j * SIG123;
#pragma unroll
    for (int m = 0; m < 4; ++m)
        sg[OFF_L3 + (a * 16 + b) * 16 + c0 + 4 * m] = s3q[m];
    if (c0 == 0) sg[OFF_L2 + a * 16 + b] = s2ab;
    if ((tid & 63) == 0) sg[a] = s1a;
}

// Chen cross-terms (S4 = [A4+B4] + A1(x)B3 + A2(x)B2 + A3(x)B1) + log
// correction. Block (j,a). Merged S1/S2/S3 in LDS (~20 KB); B3 from global
// (L2-resident). v4-proven (~8us).
__global__ __launch_bounds__(256) void k_log(const float* __restrict__ sigA,
                                             const float* __restrict__ sigB,
                                             float* __restrict__ out) {
    const int bid = blockIdx.x;
    const int j = bid >> 4;
    const int a = bid & 15;
    const int tid = threadIdx.x;
    const int q = tid >> 4;
    const int r = tid & 15;

    const float* A = sigA + (size_t)j * SIG123;
    const float* Bp = sigB + (size_t)j * SIG123;

    __shared__ float S1m[16], B1s[16], A2s[16];
    __shared__ float S2m[256], B2s[256], A3s[256];
    __shared__ float S3m[4096];

    const float b1r = Bp[r];             // B1[r]
    const float b2t = Bp[OFF_L2 + tid];  // B2[q,r]

    if (tid < 16) {
        const float bb = Bp[tid];
        B1s[tid] = bb;
        S1m[tid] = A[tid] + bb;               // S1 = A1 + B1
        A2s[tid] = A[OFF_L2 + a * 16 + tid];  // A2[a,:]
    }
    B2s[tid] = b2t;
    S2m[tid] = A[OFF_L2 + tid] + b2t + A[q] * b1r;  // S2 = A2 + B2 + A1(x)B1
    A3s[tid] = A[OFF_L3 + a * 256 + tid];           // A3[a,:,:]
#pragma unroll
    for (int k = 0; k < 16; ++k) {  // S3[p,q,r] = A3 + B3 + A1[p]B2[qr] + A2[pq]B1[r]
        const int m = k * 256 + tid;
        S3m[m] = A[OFF_L3 + m] + Bp[OFF_L3 + m] + A[k] * b2t + A[OFF_L2 + k * 16 + q] * b1r;
    }
    __syncthreads();

    const float s1a = S1m[a];
    const float A1a = A[a];
    float* outj = out + (size_t)j * OUTB;
    float* o4 = outj + OFF_L4 + a * 4096;
    const float Ac = -0.5f * s1a;

#pragma unroll
    for (int k = 0; k < 4; ++k) {
        const int f = tid + k * 256;
        const int m0 = f * 4;  // element offset: bb*256 + cc*16 + d0
        const int bb = m0 >> 8;
        const int cc = (m0 >> 4) & 15;
        const float s1b = S1m[bb], s1c = S1m[cc];
        const float s2ab = S2m[a * 16 + bb];
        const float s2bc = S2m[bb * 16 + cc];
        const float s3abc = S3m[a * 256 + (m0 >> 4)];  // merged S3[a,b,c]
        const float a3x = A3s[m0 >> 4];                // A3[a,b,c]
        const float a2x = A2s[bb];                     // A2[a,b]

        const float4 a4 = *(const float4*)(o4 + m0);            // A4+B4
        const float4 b3v = *(const float4*)(Bp + OFF_L3 + m0);  // B3[b,c,d..] (L2)
        const float4 b2v = *(const float4*)(&B2s[m0 & 255]);
        const float4 b1v = *(const float4*)(&B1s[m0 & 15]);
        const float4 v3 = *(const float4*)(&S3m[m0]);
        const float4 v2 = *(const float4*)(&S2m[m0 & 255]);
        const float4 v1 = *(const float4*)(&S1m[m0 & 15]);

        const float Bv = fmaf((1.f / 3.f) * s1a, s1b, -0.5f * s2ab);
        const float Cv = -0.5f * s3abc + (1.f / 3.f) * fmaf(s1a, s2bc, s2ab * s1c)
                         - 0.25f * s1a * s1b * s1c;
        float4 rv;
        // merged S4 = (A4+B4) + A1[a]B3[bcd] + A2[ab]B2[cd] + A3[abc]B1[d]
        rv.x = a4.x + fmaf(A1a, b3v.x, fmaf(a2x, b2v.x, a3x * b1v.x));
        rv.y = a4.y + fmaf(A1a, b3v.y, fmaf(a2x, b2v.y, a3x * b1v.y));
        rv.z = a4.z + fmaf(A1a, b3v.z, fmaf(a2x, b2v.z, a3x * b1v.z));
        rv.w = a4.w + fmaf(A1a, b3v.w, fmaf(a2x, b2v.w, a3x * b1v.w));
        // log correction
        rv.x = fmaf(Ac, v3.x, rv.x) + fmaf(Bv, v2.x, Cv * v1.x);
        rv.y = fmaf(Ac, v3.y, rv.y) + fmaf(Bv, v2.y, Cv * v1.y);
        rv.z = fmaf(Ac, v3.z, rv.z) + fmaf(Bv, v2.z, Cv * v1.z);
        rv.w = fmaf(Ac, v3.w, rv.w) + fmaf(Bv, v2.w, Cv * v1.w);
        *(float4*)(o4 + m0) = rv;
    }

    // level 3 (coalesced)
    {
        const float s1b = S1m[q], s1c = S1m[r];
        const float s2ab = S2m[a * 16 + q];
        const float s2bc = S2m[q * 16 + r];
        const float s3abc = S3m[a * 256 + tid];
        const float r3 = s3abc - 0.5f * fmaf(s1a, s2bc, s2ab * s1c)
                         + (1.f / 3.f) * s1a * s1b * s1c;
        outj[OFF_L3 + a * 256 + tid] = r3;
    }
    // level 2
    if (tid < 16) outj[OFF_L2 + a * 16 + tid] = fmaf(-0.5f * s1a, S1m[tid], S2m[a * 16 + tid]);
    // level 1
    if (tid == 0) outj[a] = s1a;
}

extern "C" void kernel_launch(void* const* d_in, const int* in_sizes, int n_in,
                              void* d_out, int out_size, void* d_ws, size_t ws_size,
                              hipStream_t stream) {
    const float* path = (const float*)d_in[0];
    float* out = (float*)d_out;
    float* ws = (float*)d_ws;
    float* sigA = ws + SIGA_OFF;
    float* sigB = ws + SIGB_OFF;

    k_scan<<<NB * 16, 128, 0, stream>>>(path, out, sigA, sigB);
    k_log<<<NB * 16, 256, 0, stream>>>(sigA, sigB, out);
}